// Round 6
// baseline (161.885 us; speedup 1.0000x reference)
//
#include <hip/hip_runtime.h>

#define NB 4
#define LB 512
#define DB 1024
#define PB 768
#define NBINS 64
#define LEN_KEEP 128          // int(512 * (1 - 0.75))
#define EPSL 1e-19f
#define WIN 10                // bins beyond +-10 spacings underflow to exact 0.0f
#define GRID2 512             // blocks in the cooperative kernel

#if defined(__has_builtin)
#if __has_builtin(__builtin_amdgcn_exp2f)
#define HAVE_EXP2 1
#endif
#endif

__device__ __forceinline__ float fast_exp2(float x) {
#ifdef HAVE_EXP2
    return __builtin_amdgcn_exp2f(x);   // raw v_exp_f32
#else
    return __expf(x * 0.69314718055994530942f);
#endif
}

// ---------------------------------------------------------------------------
// Hand-rolled grid barrier: tid0 arrives (release fence + agent atomicAdd),
// last block sets flag, everyone else spins with s_sleep backoff. Counter and
// flag are zeroed by K1 (ws is 0xAA-poisoned by the harness, so we must init).
// R3 showed the device-scope fence path is *correct*; cg::grid.sync was just
// pathologically slow (~100us). This is the minimal version.
// ---------------------------------------------------------------------------
__device__ __forceinline__ void grid_barrier(unsigned* cnt, unsigned* flag) {
    __syncthreads();
    if (threadIdx.x == 0) {
        __threadfence();   // release: all prior global writes visible
        unsigned old = __hip_atomic_fetch_add(cnt, 1u, __ATOMIC_ACQ_REL,
                                              __HIP_MEMORY_SCOPE_AGENT);
        if (old == GRID2 - 1) {
            __hip_atomic_store(flag, 1u, __ATOMIC_RELEASE,
                               __HIP_MEMORY_SCOPE_AGENT);
        } else {
            while (__hip_atomic_load(flag, __ATOMIC_RELAXED,
                                     __HIP_MEMORY_SCOPE_AGENT) == 0u) {
                __builtin_amdgcn_s_sleep(1);
            }
        }
        __threadfence();   // acquire: invalidate stale cached lines
    }
    __syncthreads();
}

// ---------------------------------------------------------------------------
// K1: min/max partials over img (256 blocks x 256 threads, float4 loads)
//     + zero the 4 barrier words used by K2.
// ---------------------------------------------------------------------------
__global__ void minmax_partial(const float4* __restrict__ v,
                               float* __restrict__ bmin, float* __restrict__ bmax,
                               unsigned* __restrict__ barr) {
    __shared__ float smin[256], smax[256];
    int tid = threadIdx.x;
    if (blockIdx.x == 0 && tid < 4) barr[tid] = 0u;
    int base = blockIdx.x * 256 + tid;
    float mn = 1e30f, mx = -1e30f;
#pragma unroll
    for (int k = 0; k < 6; ++k) {
        float4 t4 = v[base + k * 65536];
        mn = fminf(mn, fminf(fminf(t4.x, t4.y), fminf(t4.z, t4.w)));
        mx = fmaxf(mx, fmaxf(fmaxf(t4.x, t4.y), fmaxf(t4.z, t4.w)));
    }
    smin[tid] = mn; smax[tid] = mx;
    __syncthreads();
    for (int s = 128; s > 0; s >>= 1) {
        if (tid < s) {
            smin[tid] = fminf(smin[tid], smin[tid + s]);
            smax[tid] = fmaxf(smax[tid], smax[tid + s]);
        }
        __syncthreads();
    }
    if (tid == 0) { bmin[blockIdx.x] = smin[0]; bmax[blockIdx.x] = smax[0]; }
}

// ---------------------------------------------------------------------------
// K2 (cooperative, 512 blocks x 256 threads):
//   A: per-block reduce of 256 min/max partials
//   B: windowed KDE entropy for tokens 4b..4b+3 (bucket counting-sort into
//      LDS, then each lane (=bin) scans its window as ds_read_b128 chunks;
//      chunk spill values are >=10.5 spacings away -> contribute exact 0)
//   BAR1
//   C: blocks 0..7 stable rank-by-counting -> mask, ids_restore, ids_keep
//   BAR2
//   D: every block gathers one kept x row
// ---------------------------------------------------------------------------
__global__ __launch_bounds__(256, 2) void fused2(
    const float* __restrict__ x, const float* __restrict__ img,
    const float* __restrict__ bmin, const float* __restrict__ bmax,
    float* __restrict__ out_x, float* __restrict__ out_mask,
    float* __restrict__ out_rest, float* __restrict__ ws_ent,
    int* __restrict__ ids, unsigned* __restrict__ barr)
{
    __shared__ float sh[512];
    __shared__ float4 snv4[PB / 4];
    __shared__ int cnt[NBINS];
    __shared__ int bs[NBINS + 1];
    __shared__ int pos[NBINS];
    float* snv = (float*)snv4;

    int b = blockIdx.x, tid = threadIdx.x;
    int lane = tid & 63;
    int w = tid >> 6;

    // ---- A: reduce 256 partials -> vmin/vmax ----
    sh[tid] = bmin[tid]; sh[256 + tid] = bmax[tid];
    __syncthreads();
    for (int s = 128; s > 0; s >>= 1) {
        if (tid < s) {
            sh[tid]       = fminf(sh[tid], sh[tid + s]);
            sh[256 + tid] = fmaxf(sh[256 + tid], sh[256 + tid + s]);
        }
        __syncthreads();
    }
    float vmin = sh[0], vmax = sh[256];
    float inv = 1.0f / (vmax - vmin);
    const float negC = -7213.4755859375f;   // -(5000 * log2 e)
    float bv = (float)lane * (1.0f / 63.0f);

    // ---- B: entropy for 4 tokens ----
    for (int u = 0; u < 4; ++u) {
        int t = b * 4 + u;
        __syncthreads();                    // protect cnt/snv/sh reuse
        if (tid < NBINS) cnt[tid] = 0;
        __syncthreads();

        const float* row = img + (size_t)t * PB;
        float nv0 = (row[tid]       - vmin) * inv;
        float nv1 = (row[tid + 256] - vmin) * inv;
        float nv2 = (row[tid + 512] - vmin) * inv;
        int m0 = min(63, max(0, __float2int_rn(nv0 * 63.0f)));
        int m1 = min(63, max(0, __float2int_rn(nv1 * 63.0f)));
        int m2 = min(63, max(0, __float2int_rn(nv2 * 63.0f)));
        atomicAdd(&cnt[m0], 1);
        atomicAdd(&cnt[m1], 1);
        atomicAdd(&cnt[m2], 1);
        __syncthreads();

        if (tid < 64) {                     // exclusive scan (one wave)
            int c = cnt[tid];
            int incl = c;
            for (int off = 1; off < 64; off <<= 1) {
                int up = __shfl_up(incl, off, 64);
                if (tid >= off) incl += up;
            }
            bs[tid + 1] = incl;
            pos[tid] = incl - c;
            if (tid == 0) bs[0] = 0;
        }
        __syncthreads();

        snv[atomicAdd(&pos[m0], 1)] = nv0;
        snv[atomicAdd(&pos[m1], 1)] = nv1;
        snv[atomicAdd(&pos[m2], 1)] = nv2;
        __syncthreads();

        // windowed accumulation over float4 chunks, 4-wave interleave
        int c0 = bs[max(0, lane - WIN)] >> 2;
        int c1 = (bs[min(NBINS, lane + WIN + 1)] + 3) >> 2;
        float acc = 0.0f;
        for (int c = c0 + w; c < c1; c += 4) {
            float4 v = snv4[c];
            float d0 = v.x - bv, d1 = v.y - bv, d2 = v.z - bv, d3 = v.w - bv;
            acc += fast_exp2(d0 * d0 * negC);
            acc += fast_exp2(d1 * d1 * negC);
            acc += fast_exp2(d2 * d2 * negC);
            acc += fast_exp2(d3 * d3 * negC);
        }
        sh[w * NBINS + lane] = acc;
        __syncthreads();

        if (tid < 64) {
            float pdf = (sh[lane] + sh[64 + lane] + sh[128 + lane] + sh[192 + lane])
                        * (1.0f / (float)PB);
            float s = pdf;
            for (int m = 1; m < 64; m <<= 1) s += __shfl_xor(s, m, 64);
            float p = pdf / (s + EPSL) + EPSL;
            float term = p * __logf(p);
            for (int m = 1; m < 64; m <<= 1) term += __shfl_xor(term, m, 64);
            if (tid == 0) ws_ent[t] = -term;
        }
    }

    grid_barrier(barr + 0, barr + 1);

    // ---- C: stable rank (blocks 0..7), exact jnp stable-argsort semantics ----
    if (b < 8) {
        int e = b * 256 + tid;              // 0..2047
        int n = e >> 9;
        int i = e & 511;
        sh[tid]       = ws_ent[n * LB + tid];
        sh[256 + tid] = ws_ent[n * LB + 256 + tid];
        __syncthreads();
        unsigned long long ci =
            ((unsigned long long)__float_as_uint(sh[i]) << 32) | (unsigned int)i;
        int r = 0;
#pragma unroll 8
        for (int j = 0; j < LB; ++j) {      // LDS broadcast reads
            unsigned long long cj =
                ((unsigned long long)__float_as_uint(sh[j]) << 32) | (unsigned int)j;
            r += (cj < ci) ? 1 : 0;
        }
        out_rest[e] = (float)r;
        out_mask[e] = (r < LEN_KEEP) ? 0.0f : 1.0f;
        if (r < LEN_KEEP) ids[n * LEN_KEEP + r] = i;
    }

    grid_barrier(barr + 2, barr + 3);

    // ---- D: gather (block b -> output row b) ----
    {
        int n = b >> 7;
        int i = b & 127;
        int row = ids[n * LEN_KEEP + i];
        const float4* src = (const float4*)(x + ((size_t)(n * LB + row)) * DB);
        float4* dst = (float4*)(out_x + ((size_t)b) * DB);
        dst[tid] = src[tid];
    }
}

extern "C" void kernel_launch(void* const* d_in, const int* in_sizes, int n_in,
                              void* d_out, int out_size, void* d_ws, size_t ws_size,
                              hipStream_t stream) {
    const float* x   = (const float*)d_in[0];   // (4,512,1024)
    const float* img = (const float*)d_in[1];   // (4,512,768)

    float* out      = (float*)d_out;
    float* out_x    = out;                               // 4*128*1024
    float* out_mask = out + (size_t)NB * LEN_KEEP * DB;  // 4*512
    float* out_rest = out_mask + NB * LB;                // 4*512

    float*    ws   = (float*)d_ws;
    float*    bmin = ws;                      // 256
    float*    bmax = ws + 256;                // 256
    float*    ent  = ws + 512;                // 2048
    int*      ids  = (int*)(ws + 512 + NB * LB);        // 512 ints
    unsigned* barr = (unsigned*)(ws + 512 + NB * LB + 512);  // 4 words

    minmax_partial<<<256, 256, 0, stream>>>((const float4*)img, bmin, bmax, barr);

    void* args[] = { (void*)&x, (void*)&img, (void*)&bmin, (void*)&bmax,
                     (void*)&out_x, (void*)&out_mask, (void*)&out_rest,
                     (void*)&ent, (void*)&ids, (void*)&barr };
    hipLaunchCooperativeKernel((const void*)fused2, dim3(GRID2), dim3(256),
                               args, 0, stream);
}

// Round 7
// 92.283 us; speedup vs baseline: 1.7542x; 1.7542x over previous
//
#include <hip/hip_runtime.h>

#define NB 4
#define LB 512
#define DB 1024
#define PB 768
#define NBINS 64
#define LEN_KEEP 128          // int(512 * (1 - 0.75))
#define EPSL 1e-19f
#define WIN 10                // bins beyond +-10 spacings underflow to exact 0.0f

#if defined(__has_builtin)
#if __has_builtin(__builtin_amdgcn_exp2f)
#define HAVE_EXP2 1
#endif
#endif

__device__ __forceinline__ float fast_exp2(float x) {
#ifdef HAVE_EXP2
    return __builtin_amdgcn_exp2f(x);   // raw v_exp_f32
#else
    return __expf(x * 0.69314718055994530942f);
#endif
}

// ---------------------------------------------------------------------------
// K1: min/max partials over img, 64 blocks x 256 threads, float4 loads.
//     64 partials -> entropy prologue reduces them with one wave-shuffle.
// ---------------------------------------------------------------------------
__global__ void minmax_partial(const float4* __restrict__ v,
                               float* __restrict__ bmin, float* __restrict__ bmax) {
    __shared__ float smin[256], smax[256];
    int tid = threadIdx.x;
    int base = blockIdx.x * 256 + tid;
    float mn = 1e30f, mx = -1e30f;
#pragma unroll
    for (int k = 0; k < 24; ++k) {     // 64*256*24 = 393216 float4 = 1.57M floats
        float4 t4 = v[base + k * 16384];
        mn = fminf(mn, fminf(fminf(t4.x, t4.y), fminf(t4.z, t4.w)));
        mx = fmaxf(mx, fmaxf(fmaxf(t4.x, t4.y), fmaxf(t4.z, t4.w)));
    }
    smin[tid] = mn; smax[tid] = mx;
    __syncthreads();
    for (int s = 128; s > 0; s >>= 1) {
        if (tid < s) {
            smin[tid] = fminf(smin[tid], smin[tid + s]);
            smax[tid] = fmaxf(smax[tid], smax[tid + s]);
        }
        __syncthreads();
    }
    if (tid == 0) { bmin[blockIdx.x] = smin[0]; bmax[blockIdx.x] = smax[0]; }
}

// ---------------------------------------------------------------------------
// K2: windowed KDE entropy, one block per token.
//   prologue: one wave shuffle-reduces the 64 min/max partials.
//   counting-sort the 768 normalized values into 64 LDS buckets, then each
//   lane (= bin b) sums exp2(-7213.476*d^2) over buckets [b-10, b+10] only
//   (outside terms underflow to exactly 0.0f in f32 -> numerically exact).
//   Window reads are scalar ds_read_b32 (R6 showed b128 here = 8-way bank
//   conflicts, ~1M SQ_LDS_BANK_CONFLICT; b32 spread is ~2-way = free).
// ---------------------------------------------------------------------------
__global__ void entropy_kernel(const float* __restrict__ img,
                               const float* __restrict__ bmin,
                               const float* __restrict__ bmax,
                               float* __restrict__ ent) {
    __shared__ float sh[256];        // wave bin partials (also vmin/vmax bcast)
    __shared__ float snv[PB];        // bucket-sorted normalized values
    __shared__ int   cnt[NBINS];     // bucket counts
    __shared__ int   bs[NBINS + 1];  // bucket start offsets (exclusive scan)
    __shared__ int   pos[NBINS];     // running scatter cursors

    int t = blockIdx.x;              // token 0..2047
    int tid = threadIdx.x;
    int lane = tid & 63;
    int w = tid >> 6;

    if (tid < NBINS) cnt[tid] = 0;
    // ---- reduce 64 partials -> vmin/vmax (wave 0) ----
    if (tid < 64) {
        float mn = bmin[tid], mx = bmax[tid];
        for (int m = 1; m < 64; m <<= 1) {
            mn = fminf(mn, __shfl_xor(mn, m, 64));
            mx = fmaxf(mx, __shfl_xor(mx, m, 64));
        }
        if (tid == 0) { sh[0] = mn; sh[1] = mx; }
    }
    __syncthreads();
    float vmin = sh[0], vmax = sh[1];
    float inv = 1.0f / (vmax - vmin);

    // ---- load my 3 values, normalize, count buckets ----
    const float* row = img + (size_t)t * PB;
    float nv0 = (row[tid]       - vmin) * inv;
    float nv1 = (row[tid + 256] - vmin) * inv;
    float nv2 = (row[tid + 512] - vmin) * inv;
    int m0 = min(63, max(0, __float2int_rn(nv0 * 63.0f)));
    int m1 = min(63, max(0, __float2int_rn(nv1 * 63.0f)));
    int m2 = min(63, max(0, __float2int_rn(nv2 * 63.0f)));
    atomicAdd(&cnt[m0], 1);
    atomicAdd(&cnt[m1], 1);
    atomicAdd(&cnt[m2], 1);
    __syncthreads();

    // ---- exclusive scan of bucket counts (one wave) ----
    if (tid < 64) {
        int c = cnt[tid];
        int incl = c;
        for (int off = 1; off < 64; off <<= 1) {
            int up = __shfl_up(incl, off, 64);
            if (tid >= off) incl += up;
        }
        bs[tid + 1] = incl;
        pos[tid] = incl - c;       // exclusive prefix
        if (tid == 0) bs[0] = 0;
    }
    __syncthreads();

    // ---- scatter values into bucket-sorted order ----
    snv[atomicAdd(&pos[m0], 1)] = nv0;
    snv[atomicAdd(&pos[m1], 1)] = nv1;
    snv[atomicAdd(&pos[m2], 1)] = nv2;
    __syncthreads();

    // ---- windowed accumulation: lane = bin, 4 waves take stride-4 slices ----
    float bv = (float)lane * (1.0f / 63.0f);
    int lo = bs[max(0, lane - WIN)];
    int hi = bs[min(NBINS, lane + WIN + 1)];
    const float negC = -7213.4755859375f;   // -(5000 * log2 e)
    float acc0 = 0.0f, acc1 = 0.0f;
    int j = lo + w;
    for (; j + 4 < hi; j += 8) {
        float d0 = snv[j] - bv;
        float d1 = snv[j + 4] - bv;
        acc0 += fast_exp2(d0 * d0 * negC);
        acc1 += fast_exp2(d1 * d1 * negC);
    }
    if (j < hi) {
        float d0 = snv[j] - bv;
        acc0 += fast_exp2(d0 * d0 * negC);
    }
    sh[w * NBINS + lane] = acc0 + acc1;
    __syncthreads();

    // ---- finish: pdf normalize + entropy (one wavefront) ----
    if (tid < 64) {
        float pdf = (sh[lane] + sh[64 + lane] + sh[128 + lane] + sh[192 + lane])
                    * (1.0f / (float)PB);
        float s = pdf;
        for (int m = 1; m < 64; m <<= 1) s += __shfl_xor(s, m, 64);
        float p = pdf / (s + EPSL) + EPSL;
        float term = p * __logf(p);
        for (int m = 1; m < 64; m <<= 1) term += __shfl_xor(term, m, 64);
        if (tid == 0) ent[t] = -term;
    }
}

// ---------------------------------------------------------------------------
// K3: fused rank + gather. 512 blocks (one per output row), 256 threads.
// Each block stages its entropy row in LDS and ranks all 512 elements
// (stable u64 composite = exact jnp.argsort semantics; LDS reads are
// wave-uniform broadcasts, conflict-free). Blocks with slot==0 write
// mask/ids_restore; every block then gathers the x row with rank == slot.
// ---------------------------------------------------------------------------
__global__ void rank_gather_kernel(const float* __restrict__ x,
                                   const float* __restrict__ ent,
                                   float* __restrict__ out_x,
                                   float* __restrict__ out_mask,
                                   float* __restrict__ out_rest) {
    __shared__ float sh[LB];
    __shared__ int skeep;
    int b = blockIdx.x, tid = threadIdx.x;
    int n = b >> 7;              // row 0..3
    int i = b & 127;             // output slot 0..127

    sh[tid]       = ent[n * LB + tid];
    sh[256 + tid] = ent[n * LB + 256 + tid];
    __syncthreads();

    unsigned long long c0 =
        ((unsigned long long)__float_as_uint(sh[tid]) << 32) | (unsigned int)tid;
    unsigned long long c1 =
        ((unsigned long long)__float_as_uint(sh[256 + tid]) << 32) | (unsigned int)(256 + tid);
    int r0 = 0, r1 = 0;
#pragma unroll 8
    for (int j = 0; j < LB; ++j) {   // broadcast LDS reads
        unsigned long long cj =
            ((unsigned long long)__float_as_uint(sh[j]) << 32) | (unsigned int)j;
        r0 += (cj < c0) ? 1 : 0;
        r1 += (cj < c1) ? 1 : 0;
    }
    if (r0 == i) skeep = tid;        // exactly one thread in the block hits
    if (r1 == i) skeep = 256 + tid;
    if (i == 0) {                    // 4 blocks write the row-wide outputs
        out_rest[n * LB + tid]        = (float)r0;
        out_rest[n * LB + 256 + tid]  = (float)r1;
        out_mask[n * LB + tid]        = (r0 < LEN_KEEP) ? 0.0f : 1.0f;
        out_mask[n * LB + 256 + tid]  = (r1 < LEN_KEEP) ? 0.0f : 1.0f;
    }
    __syncthreads();

    int row = skeep;
    const float4* src = (const float4*)(x + ((size_t)(n * LB + row)) * DB);
    float4* dst = (float4*)(out_x + ((size_t)b) * DB);
    dst[tid] = src[tid];
}

extern "C" void kernel_launch(void* const* d_in, const int* in_sizes, int n_in,
                              void* d_out, int out_size, void* d_ws, size_t ws_size,
                              hipStream_t stream) {
    const float* x   = (const float*)d_in[0];   // (4,512,1024)
    const float* img = (const float*)d_in[1];   // (4,512,768)

    float* out      = (float*)d_out;
    float* out_x    = out;                               // 4*128*1024
    float* out_mask = out + (size_t)NB * LEN_KEEP * DB;  // 4*512
    float* out_rest = out_mask + NB * LB;                // 4*512

    float* ws   = (float*)d_ws;
    float* bmin = ws;            // 64
    float* bmax = ws + 64;       // 64
    float* ent  = ws + 128;      // 2048

    minmax_partial<<<64, 256, 0, stream>>>((const float4*)img, bmin, bmax);
    entropy_kernel<<<NB * LB, 256, 0, stream>>>(img, bmin, bmax, ent);
    rank_gather_kernel<<<dim3(NB * LEN_KEEP), 256, 0, stream>>>(x, ent, out_x, out_mask, out_rest);
}

// Round 8
// 80.164 us; speedup vs baseline: 2.0194x; 1.1512x over previous
//
#include <hip/hip_runtime.h>

#define NB 4
#define LB 512
#define DB 1024
#define PB 768
#define NBINS 64
#define LEN_KEEP 128          // int(512 * (1 - 0.75))
#define EPSL 1e-19f
#define WIN 6                 // bucket b+-7 values are >=6.5 spacings away:
                              // kern <= 2^-77, absorbed below f32 ulp of the
                              // per-slice accumulator (>=O(1)) -> exact

#if defined(__has_builtin)
#if __has_builtin(__builtin_amdgcn_exp2f)
#define HAVE_EXP2 1
#endif
#endif

__device__ __forceinline__ float fast_exp2(float x) {
#ifdef HAVE_EXP2
    return __builtin_amdgcn_exp2f(x);   // raw v_exp_f32
#else
    return __expf(x * 0.69314718055994530942f);
#endif
}

// ---------------------------------------------------------------------------
// K1: min/max partials over img, 64 blocks x 256 threads, float4 loads.
//     64 partials -> entropy prologue reduces them with one wave-shuffle.
// ---------------------------------------------------------------------------
__global__ void minmax_partial(const float4* __restrict__ v,
                               float* __restrict__ bmin, float* __restrict__ bmax) {
    __shared__ float smin[256], smax[256];
    int tid = threadIdx.x;
    int base = blockIdx.x * 256 + tid;
    float mn = 1e30f, mx = -1e30f;
#pragma unroll
    for (int k = 0; k < 24; ++k) {     // 64*256*24 = 393216 float4 = 1.57M floats
        float4 t4 = v[base + k * 16384];
        mn = fminf(mn, fminf(fminf(t4.x, t4.y), fminf(t4.z, t4.w)));
        mx = fmaxf(mx, fmaxf(fmaxf(t4.x, t4.y), fmaxf(t4.z, t4.w)));
    }
    smin[tid] = mn; smax[tid] = mx;
    __syncthreads();
    for (int s = 128; s > 0; s >>= 1) {
        if (tid < s) {
            smin[tid] = fminf(smin[tid], smin[tid + s]);
            smax[tid] = fmaxf(smax[tid], smax[tid + s]);
        }
        __syncthreads();
    }
    if (tid == 0) { bmin[blockIdx.x] = smin[0]; bmax[blockIdx.x] = smax[0]; }
}

// ---------------------------------------------------------------------------
// K2: windowed KDE entropy, one block per token.
//   prologue: one wave shuffle-reduces the 64 min/max partials.
//   counting-sort the 768 normalized values into 64 LDS buckets, then each
//   lane (= bin b) sums exp2(-7213.476*d^2) over buckets [b-WIN, b+WIN].
//   Window reads are scalar ds_read_b32 (R6: b128 here = 8-way conflicts).
//   Single accumulator, stride-4 wave interleave — same j-order as R5.
// ---------------------------------------------------------------------------
__global__ void entropy_kernel(const float* __restrict__ img,
                               const float* __restrict__ bmin,
                               const float* __restrict__ bmax,
                               float* __restrict__ ent) {
    __shared__ float sh[256];        // vmin/vmax bcast, then wave bin partials
    __shared__ float snv[PB];        // bucket-sorted normalized values
    __shared__ int   cnt[NBINS];     // bucket counts
    __shared__ int   bs[NBINS + 1];  // bucket start offsets (exclusive scan)
    __shared__ int   pos[NBINS];     // running scatter cursors

    int t = blockIdx.x;              // token 0..2047
    int tid = threadIdx.x;
    int lane = tid & 63;
    int w = tid >> 6;

    if (tid < NBINS) cnt[tid] = 0;
    // ---- reduce 64 partials -> vmin/vmax (wave 0) ----
    if (tid < 64) {
        float mn = bmin[tid], mx = bmax[tid];
        for (int m = 1; m < 64; m <<= 1) {
            mn = fminf(mn, __shfl_xor(mn, m, 64));
            mx = fmaxf(mx, __shfl_xor(mx, m, 64));
        }
        if (tid == 0) { sh[0] = mn; sh[1] = mx; }
    }
    __syncthreads();
    float vmin = sh[0], vmax = sh[1];
    float inv = 1.0f / (vmax - vmin);

    // ---- load my 3 values, normalize, count buckets ----
    const float* row = img + (size_t)t * PB;
    float nv0 = (row[tid]       - vmin) * inv;
    float nv1 = (row[tid + 256] - vmin) * inv;
    float nv2 = (row[tid + 512] - vmin) * inv;
    int m0 = min(63, max(0, __float2int_rn(nv0 * 63.0f)));
    int m1 = min(63, max(0, __float2int_rn(nv1 * 63.0f)));
    int m2 = min(63, max(0, __float2int_rn(nv2 * 63.0f)));
    atomicAdd(&cnt[m0], 1);
    atomicAdd(&cnt[m1], 1);
    atomicAdd(&cnt[m2], 1);
    __syncthreads();

    // ---- exclusive scan of bucket counts (one wave) ----
    if (tid < 64) {
        int c = cnt[tid];
        int incl = c;
        for (int off = 1; off < 64; off <<= 1) {
            int up = __shfl_up(incl, off, 64);
            if (tid >= off) incl += up;
        }
        bs[tid + 1] = incl;
        pos[tid] = incl - c;       // exclusive prefix
        if (tid == 0) bs[0] = 0;
    }
    __syncthreads();

    // ---- scatter values into bucket-sorted order ----
    snv[atomicAdd(&pos[m0], 1)] = nv0;
    snv[atomicAdd(&pos[m1], 1)] = nv1;
    snv[atomicAdd(&pos[m2], 1)] = nv2;
    __syncthreads();

    // ---- windowed accumulation: lane = bin, 4 waves take stride-4 slices ----
    float bv = (float)lane * (1.0f / 63.0f);
    int lo = bs[max(0, lane - WIN)];
    int hi = bs[min(NBINS, lane + WIN + 1)];
    const float negC = -7213.4755859375f;   // -(5000 * log2 e)
    float acc = 0.0f;
    for (int j = lo + w; j < hi; j += 4) {
        float d = snv[j] - bv;
        acc += fast_exp2(d * d * negC);
    }
    sh[w * NBINS + lane] = acc;
    __syncthreads();

    // ---- finish: pdf normalize + entropy (one wavefront) ----
    if (tid < 64) {
        float pdf = (sh[lane] + sh[64 + lane] + sh[128 + lane] + sh[192 + lane])
                    * (1.0f / (float)PB);
        float s = pdf;
        for (int m = 1; m < 64; m <<= 1) s += __shfl_xor(s, m, 64);
        float p = pdf / (s + EPSL) + EPSL;
        float term = p * __logf(p);
        for (int m = 1; m < 64; m <<= 1) term += __shfl_xor(term, m, 64);
        if (tid == 0) ent[t] = -term;
    }
}

// ---------------------------------------------------------------------------
// K3: stable rank-by-counting, 16 blocks x 256 threads, 2 threads/element.
//     Row staged in LDS; u64 (key,idx) composite = exact jnp stable argsort.
//     Thread pair (tid, tid^1) scans halves of j, combined via shfl_xor.
// ---------------------------------------------------------------------------
__global__ void rank_kernel(const float* __restrict__ ent,
                            int* __restrict__ ids_keep,
                            float* __restrict__ out_mask,
                            float* __restrict__ out_restore) {
    __shared__ float sh[LB];
    int b = blockIdx.x, tid = threadIdx.x;
    int n = b >> 2;                       // row 0..3 (uniform per block)
    int i = (b & 3) * 128 + (tid >> 1);   // element in row
    int half = tid & 1;                   // which 256-wide j slice

    sh[tid]       = ent[n * LB + tid];
    sh[256 + tid] = ent[n * LB + 256 + tid];
    __syncthreads();

    unsigned long long ci =
        ((unsigned long long)__float_as_uint(sh[i]) << 32) | (unsigned int)i;
    int r = 0;
    int j0 = half * 256;
#pragma unroll 8
    for (int j = j0; j < j0 + 256; ++j) {     // LDS broadcast reads
        unsigned long long cj =
            ((unsigned long long)__float_as_uint(sh[j]) << 32) | (unsigned int)j;
        r += (cj < ci) ? 1 : 0;
    }
    r += __shfl_xor(r, 1, 64);                // combine the two halves
    if (half == 0) {
        out_restore[n * LB + i] = (float)r;
        out_mask[n * LB + i] = (r < LEN_KEEP) ? 0.0f : 1.0f;
        if (r < LEN_KEEP) ids_keep[n * LEN_KEEP + r] = i;
    }
}

// ---------------------------------------------------------------------------
// K4: gather kept rows of x: block (i, n), 256 threads x float4 = 1024 floats
// ---------------------------------------------------------------------------
__global__ void gather_kernel(const float* __restrict__ x,
                              const int* __restrict__ ids_keep,
                              float* __restrict__ out) {
    int i = blockIdx.x;    // 0..127
    int n = blockIdx.y;    // 0..3
    int row = ids_keep[n * LEN_KEEP + i];
    const float4* src = (const float4*)(x + ((size_t)(n * LB + row)) * DB);
    float4* dst = (float4*)(out + ((size_t)(n * LEN_KEEP + i)) * DB);
    dst[threadIdx.x] = src[threadIdx.x];
}

extern "C" void kernel_launch(void* const* d_in, const int* in_sizes, int n_in,
                              void* d_out, int out_size, void* d_ws, size_t ws_size,
                              hipStream_t stream) {
    const float* x   = (const float*)d_in[0];   // (4,512,1024)
    const float* img = (const float*)d_in[1];   // (4,512,768)

    float* out      = (float*)d_out;
    float* out_x    = out;                               // 4*128*1024
    float* out_mask = out + (size_t)NB * LEN_KEEP * DB;  // 4*512
    float* out_rest = out_mask + NB * LB;                // 4*512

    float* ws   = (float*)d_ws;
    float* bmin = ws;            // 64
    float* bmax = ws + 64;       // 64
    float* ent  = ws + 128;      // 2048
    int*   ids  = (int*)(ws + 128 + NB * LB);  // 512 ints

    minmax_partial<<<64, 256, 0, stream>>>((const float4*)img, bmin, bmax);
    entropy_kernel<<<NB * LB, 256, 0, stream>>>(img, bmin, bmax, ent);
    rank_kernel<<<16, 256, 0, stream>>>(ent, ids, out_mask, out_rest);
    gather_kernel<<<dim3(LEN_KEEP, NB), 256, 0, stream>>>(x, ids, out_x);
}

// Round 9
// 78.902 us; speedup vs baseline: 2.0517x; 1.0160x over previous
//
#include <hip/hip_runtime.h>

#define NB 4
#define LB 512
#define DB 1024
#define PB 768
#define NBINS 64
#define LEN_KEEP 128          // int(512 * (1 - 0.75))
#define EPSL 1e-19f
#define WIN 4                 // excluded buckets are >=4.5 spacings away:
                              // kern <= 2^-36.8 ~ 8e-12 vs per-bin sums O(10)
                              // -> relative error ~1e-9, below reorder noise

#if defined(__has_builtin)
#if __has_builtin(__builtin_amdgcn_exp2f)
#define HAVE_EXP2 1
#endif
#endif

__device__ __forceinline__ float fast_exp2(float x) {
#ifdef HAVE_EXP2
    return __builtin_amdgcn_exp2f(x);   // raw v_exp_f32
#else
    return __expf(x * 0.69314718055994530942f);
#endif
}

// ---------------------------------------------------------------------------
// K1: min/max partials over img, 64 blocks x 256 threads, float4 loads.
//     64 partials -> entropy prologue reduces them with one wave-shuffle.
// ---------------------------------------------------------------------------
__global__ void minmax_partial(const float4* __restrict__ v,
                               float* __restrict__ bmin, float* __restrict__ bmax) {
    __shared__ float smin[256], smax[256];
    int tid = threadIdx.x;
    int base = blockIdx.x * 256 + tid;
    float mn = 1e30f, mx = -1e30f;
#pragma unroll
    for (int k = 0; k < 24; ++k) {     // 64*256*24 = 393216 float4 = 1.57M floats
        float4 t4 = v[base + k * 16384];
        mn = fminf(mn, fminf(fminf(t4.x, t4.y), fminf(t4.z, t4.w)));
        mx = fmaxf(mx, fmaxf(fmaxf(t4.x, t4.y), fmaxf(t4.z, t4.w)));
    }
    smin[tid] = mn; smax[tid] = mx;
    __syncthreads();
    for (int s = 128; s > 0; s >>= 1) {
        if (tid < s) {
            smin[tid] = fminf(smin[tid], smin[tid + s]);
            smax[tid] = fmaxf(smax[tid], smax[tid + s]);
        }
        __syncthreads();
    }
    if (tid == 0) { bmin[blockIdx.x] = smin[0]; bmax[blockIdx.x] = smax[0]; }
}

// ---------------------------------------------------------------------------
// K2: windowed KDE entropy, one block per token.
//   prologue: one wave shuffle-reduces the 64 min/max partials.
//   counting-sort the 768 normalized values into 64 LDS buckets, then each
//   lane (= bin b) sums exp2(-7213.476*d^2) over buckets [b-WIN, b+WIN].
//   Window reads are scalar ds_read_b32 (R6: b128 here = 8-way conflicts).
//   Single accumulator, stride-4 wave interleave — same j-order as R5/R8.
// ---------------------------------------------------------------------------
__global__ void entropy_kernel(const float* __restrict__ img,
                               const float* __restrict__ bmin,
                               const float* __restrict__ bmax,
                               float* __restrict__ ent) {
    __shared__ float sh[256];        // vmin/vmax bcast, then wave bin partials
    __shared__ float snv[PB];        // bucket-sorted normalized values
    __shared__ int   cnt[NBINS];     // bucket counts
    __shared__ int   bs[NBINS + 1];  // bucket start offsets (exclusive scan)
    __shared__ int   pos[NBINS];     // running scatter cursors

    int t = blockIdx.x;              // token 0..2047
    int tid = threadIdx.x;
    int lane = tid & 63;
    int w = tid >> 6;

    if (tid < NBINS) cnt[tid] = 0;
    // ---- reduce 64 partials -> vmin/vmax (wave 0) ----
    if (tid < 64) {
        float mn = bmin[tid], mx = bmax[tid];
        for (int m = 1; m < 64; m <<= 1) {
            mn = fminf(mn, __shfl_xor(mn, m, 64));
            mx = fmaxf(mx, __shfl_xor(mx, m, 64));
        }
        if (tid == 0) { sh[0] = mn; sh[1] = mx; }
    }
    __syncthreads();
    float vmin = sh[0], vmax = sh[1];
    float inv = 1.0f / (vmax - vmin);

    // ---- load my 3 values, normalize, count buckets ----
    const float* row = img + (size_t)t * PB;
    float nv0 = (row[tid]       - vmin) * inv;
    float nv1 = (row[tid + 256] - vmin) * inv;
    float nv2 = (row[tid + 512] - vmin) * inv;
    int m0 = min(63, max(0, __float2int_rn(nv0 * 63.0f)));
    int m1 = min(63, max(0, __float2int_rn(nv1 * 63.0f)));
    int m2 = min(63, max(0, __float2int_rn(nv2 * 63.0f)));
    atomicAdd(&cnt[m0], 1);
    atomicAdd(&cnt[m1], 1);
    atomicAdd(&cnt[m2], 1);
    __syncthreads();

    // ---- exclusive scan of bucket counts (one wave) ----
    if (tid < 64) {
        int c = cnt[tid];
        int incl = c;
        for (int off = 1; off < 64; off <<= 1) {
            int up = __shfl_up(incl, off, 64);
            if (tid >= off) incl += up;
        }
        bs[tid + 1] = incl;
        pos[tid] = incl - c;       // exclusive prefix
        if (tid == 0) bs[0] = 0;
    }
    __syncthreads();

    // ---- scatter values into bucket-sorted order ----
    snv[atomicAdd(&pos[m0], 1)] = nv0;
    snv[atomicAdd(&pos[m1], 1)] = nv1;
    snv[atomicAdd(&pos[m2], 1)] = nv2;
    __syncthreads();

    // ---- windowed accumulation: lane = bin, 4 waves take stride-4 slices ----
    float bv = (float)lane * (1.0f / 63.0f);
    int lo = bs[max(0, lane - WIN)];
    int hi = bs[min(NBINS, lane + WIN + 1)];
    const float negC = -7213.4755859375f;   // -(5000 * log2 e)
    float acc = 0.0f;
    for (int j = lo + w; j < hi; j += 4) {
        float d = snv[j] - bv;
        acc += fast_exp2(d * d * negC);
    }
    sh[w * NBINS + lane] = acc;
    __syncthreads();

    // ---- finish: pdf normalize + entropy (one wavefront) ----
    if (tid < 64) {
        float pdf = (sh[lane] + sh[64 + lane] + sh[128 + lane] + sh[192 + lane])
                    * (1.0f / (float)PB);
        float s = pdf;
        for (int m = 1; m < 64; m <<= 1) s += __shfl_xor(s, m, 64);
        float p = pdf / (s + EPSL) + EPSL;
        float term = p * __logf(p);
        for (int m = 1; m < 64; m <<= 1) term += __shfl_xor(term, m, 64);
        if (tid == 0) ent[t] = -term;
    }
}

// ---------------------------------------------------------------------------
// K3: stable rank-by-counting, 16 blocks x 256 threads, 2 threads/element.
//     Row staged in LDS; u64 (key,idx) composite = exact jnp stable argsort.
//     Thread pair (tid, tid^1) scans halves of j, combined via shfl_xor.
// ---------------------------------------------------------------------------
__global__ void rank_kernel(const float* __restrict__ ent,
                            int* __restrict__ ids_keep,
                            float* __restrict__ out_mask,
                            float* __restrict__ out_restore) {
    __shared__ float sh[LB];
    int b = blockIdx.x, tid = threadIdx.x;
    int n = b >> 2;                       // row 0..3 (uniform per block)
    int i = (b & 3) * 128 + (tid >> 1);   // element in row
    int half = tid & 1;                   // which 256-wide j slice

    sh[tid]       = ent[n * LB + tid];
    sh[256 + tid] = ent[n * LB + 256 + tid];
    __syncthreads();

    unsigned long long ci =
        ((unsigned long long)__float_as_uint(sh[i]) << 32) | (unsigned int)i;
    int r = 0;
    int j0 = half * 256;
#pragma unroll 8
    for (int j = j0; j < j0 + 256; ++j) {     // LDS broadcast reads
        unsigned long long cj =
            ((unsigned long long)__float_as_uint(sh[j]) << 32) | (unsigned int)j;
        r += (cj < ci) ? 1 : 0;
    }
    r += __shfl_xor(r, 1, 64);                // combine the two halves
    if (half == 0) {
        out_restore[n * LB + i] = (float)r;
        out_mask[n * LB + i] = (r < LEN_KEEP) ? 0.0f : 1.0f;
        if (r < LEN_KEEP) ids_keep[n * LEN_KEEP + r] = i;
    }
}

// ---------------------------------------------------------------------------
// K4: gather kept rows of x: block (i, n), 256 threads x float4 = 1024 floats
// ---------------------------------------------------------------------------
__global__ void gather_kernel(const float* __restrict__ x,
                              const int* __restrict__ ids_keep,
                              float* __restrict__ out) {
    int i = blockIdx.x;    // 0..127
    int n = blockIdx.y;    // 0..3
    int row = ids_keep[n * LEN_KEEP + i];
    const float4* src = (const float4*)(x + ((size_t)(n * LB + row)) * DB);
    float4* dst = (float4*)(out + ((size_t)(n * LEN_KEEP + i)) * DB);
    dst[threadIdx.x] = src[threadIdx.x];
}

extern "C" void kernel_launch(void* const* d_in, const int* in_sizes, int n_in,
                              void* d_out, int out_size, void* d_ws, size_t ws_size,
                              hipStream_t stream) {
    const float* x   = (const float*)d_in[0];   // (4,512,1024)
    const float* img = (const float*)d_in[1];   // (4,512,768)

    float* out      = (float*)d_out;
    float* out_x    = out;                               // 4*128*1024
    float* out_mask = out + (size_t)NB * LEN_KEEP * DB;  // 4*512
    float* out_rest = out_mask + NB * LB;                // 4*512

    float* ws   = (float*)d_ws;
    float* bmin = ws;            // 64
    float* bmax = ws + 64;       // 64
    float* ent  = ws + 128;      // 2048
    int*   ids  = (int*)(ws + 128 + NB * LB);  // 512 ints

    minmax_partial<<<64, 256, 0, stream>>>((const float4*)img, bmin, bmax);
    entropy_kernel<<<NB * LB, 256, 0, stream>>>(img, bmin, bmax, ent);
    rank_kernel<<<16, 256, 0, stream>>>(ent, ids, out_mask, out_rest);
    gather_kernel<<<dim3(LEN_KEEP, NB), 256, 0, stream>>>(x, ids, out_x);
}

// Round 10
// 76.528 us; speedup vs baseline: 2.1154x; 1.0310x over previous
//
#include <hip/hip_runtime.h>

#define NB 4
#define LB 512
#define DB 1024
#define PB 768
#define NBINS 64
#define LEN_KEEP 128          // int(512 * (1 - 0.75))
#define EPSL 1e-19f
#define WIN 3                 // excluded buckets are >=3.5 spacings away:
                              // kern <= 2^-22.3 ~ 2e-7; dropped mass ~1e-5
                              // vs per-bin sums O(10) -> ~1e-6 relative

#if defined(__has_builtin)
#if __has_builtin(__builtin_amdgcn_exp2f)
#define HAVE_EXP2 1
#endif
#endif

__device__ __forceinline__ float fast_exp2(float x) {
#ifdef HAVE_EXP2
    return __builtin_amdgcn_exp2f(x);   // raw v_exp_f32
#else
    return __expf(x * 0.69314718055994530942f);
#endif
}

// ---------------------------------------------------------------------------
// K1: min/max partials over img, 64 blocks x 256 threads, float4 loads.
//     64 partials -> entropy prologue reduces them with one wave-shuffle.
// ---------------------------------------------------------------------------
__global__ void minmax_partial(const float4* __restrict__ v,
                               float* __restrict__ bmin, float* __restrict__ bmax) {
    __shared__ float smin[256], smax[256];
    int tid = threadIdx.x;
    int base = blockIdx.x * 256 + tid;
    float mn = 1e30f, mx = -1e30f;
#pragma unroll
    for (int k = 0; k < 24; ++k) {     // 64*256*24 = 393216 float4 = 1.57M floats
        float4 t4 = v[base + k * 16384];
        mn = fminf(mn, fminf(fminf(t4.x, t4.y), fminf(t4.z, t4.w)));
        mx = fmaxf(mx, fmaxf(fmaxf(t4.x, t4.y), fmaxf(t4.z, t4.w)));
    }
    smin[tid] = mn; smax[tid] = mx;
    __syncthreads();
    for (int s = 128; s > 0; s >>= 1) {
        if (tid < s) {
            smin[tid] = fminf(smin[tid], smin[tid + s]);
            smax[tid] = fmaxf(smax[tid], smax[tid + s]);
        }
        __syncthreads();
    }
    if (tid == 0) { bmin[blockIdx.x] = smin[0]; bmax[blockIdx.x] = smax[0]; }
}

// ---------------------------------------------------------------------------
// K2: windowed KDE entropy, one block per token.
//   prologue: one wave shuffle-reduces the 64 min/max partials.
//   counting-sort the 768 normalized values into 64 LDS buckets, then each
//   lane (= bin b) sums exp2(-7213.476*d^2) over buckets [b-WIN, b+WIN].
//   Window reads are scalar ds_read_b32 (R6: b128 here = 8-way conflicts).
//   Single accumulator, stride-4 wave interleave — same j-order as R5/R8/R9.
// ---------------------------------------------------------------------------
__global__ void entropy_kernel(const float* __restrict__ img,
                               const float* __restrict__ bmin,
                               const float* __restrict__ bmax,
                               float* __restrict__ ent) {
    __shared__ float sh[256];        // vmin/vmax bcast, then wave bin partials
    __shared__ float snv[PB];        // bucket-sorted normalized values
    __shared__ int   cnt[NBINS];     // bucket counts
    __shared__ int   bs[NBINS + 1];  // bucket start offsets (exclusive scan)
    __shared__ int   pos[NBINS];     // running scatter cursors

    int t = blockIdx.x;              // token 0..2047
    int tid = threadIdx.x;
    int lane = tid & 63;
    int w = tid >> 6;

    if (tid < NBINS) cnt[tid] = 0;
    // ---- reduce 64 partials -> vmin/vmax (wave 0) ----
    if (tid < 64) {
        float mn = bmin[tid], mx = bmax[tid];
        for (int m = 1; m < 64; m <<= 1) {
            mn = fminf(mn, __shfl_xor(mn, m, 64));
            mx = fmaxf(mx, __shfl_xor(mx, m, 64));
        }
        if (tid == 0) { sh[0] = mn; sh[1] = mx; }
    }
    __syncthreads();
    float vmin = sh[0], vmax = sh[1];
    float inv = 1.0f / (vmax - vmin);

    // ---- load my 3 values, normalize, count buckets ----
    const float* row = img + (size_t)t * PB;
    float nv0 = (row[tid]       - vmin) * inv;
    float nv1 = (row[tid + 256] - vmin) * inv;
    float nv2 = (row[tid + 512] - vmin) * inv;
    int m0 = min(63, max(0, __float2int_rn(nv0 * 63.0f)));
    int m1 = min(63, max(0, __float2int_rn(nv1 * 63.0f)));
    int m2 = min(63, max(0, __float2int_rn(nv2 * 63.0f)));
    atomicAdd(&cnt[m0], 1);
    atomicAdd(&cnt[m1], 1);
    atomicAdd(&cnt[m2], 1);
    __syncthreads();

    // ---- exclusive scan of bucket counts (one wave) ----
    if (tid < 64) {
        int c = cnt[tid];
        int incl = c;
        for (int off = 1; off < 64; off <<= 1) {
            int up = __shfl_up(incl, off, 64);
            if (tid >= off) incl += up;
        }
        bs[tid + 1] = incl;
        pos[tid] = incl - c;       // exclusive prefix
        if (tid == 0) bs[0] = 0;
    }
    __syncthreads();

    // ---- scatter values into bucket-sorted order ----
    snv[atomicAdd(&pos[m0], 1)] = nv0;
    snv[atomicAdd(&pos[m1], 1)] = nv1;
    snv[atomicAdd(&pos[m2], 1)] = nv2;
    __syncthreads();

    // ---- windowed accumulation: lane = bin, 4 waves take stride-4 slices ----
    float bv = (float)lane * (1.0f / 63.0f);
    int lo = bs[max(0, lane - WIN)];
    int hi = bs[min(NBINS, lane + WIN + 1)];
    const float negC = -7213.4755859375f;   // -(5000 * log2 e)
    float acc = 0.0f;
    for (int j = lo + w; j < hi; j += 4) {
        float d = snv[j] - bv;
        acc += fast_exp2(d * d * negC);
    }
    sh[w * NBINS + lane] = acc;
    __syncthreads();

    // ---- finish: pdf normalize + entropy (one wavefront) ----
    if (tid < 64) {
        float pdf = (sh[lane] + sh[64 + lane] + sh[128 + lane] + sh[192 + lane])
                    * (1.0f / (float)PB);
        float s = pdf;
        for (int m = 1; m < 64; m <<= 1) s += __shfl_xor(s, m, 64);
        float p = pdf / (s + EPSL) + EPSL;
        float term = p * __logf(p);
        for (int m = 1; m < 64; m <<= 1) term += __shfl_xor(term, m, 64);
        if (tid == 0) ent[t] = -term;
    }
}

// ---------------------------------------------------------------------------
// K3: fused stable-rank + self-owned gather. 128 blocks x 256 threads.
//   Block b handles row n = b>>5, elements i in [(b&31)*16, +16).
//   16 threads/element: thread slice = tid&15 scans 32 j's; 4-step shfl_xor
//   combine (16-lane groups are wave-internal). Zero redundant rank work
//   (R4/R7 lesson). Each block then gathers ONLY the x rows it ranked kept
//   (avg 4, max 16) via an LDS-compacted (slot,row) list — one row per
//   iteration, 256 threads x float4. Kills the separate gather dispatch
//   while keeping copy parallelism at 128 blocks.
// ---------------------------------------------------------------------------
__global__ void rank_gather_kernel(const float* __restrict__ x,
                                   const float* __restrict__ ent,
                                   float* __restrict__ out_x,
                                   float* __restrict__ out_mask,
                                   float* __restrict__ out_rest) {
    __shared__ float sh[LB];
    __shared__ int keep_list[16];    // (slot<<16) | row_idx
    __shared__ int nkeep;
    int b = blockIdx.x, tid = threadIdx.x;
    int n = b >> 5;                       // row 0..3 (uniform per block)
    int i = (b & 31) * 16 + (tid >> 4);   // element in row (16 per block)
    int slice = tid & 15;                 // j-slice

    if (tid == 0) nkeep = 0;
    sh[tid]       = ent[n * LB + tid];
    sh[256 + tid] = ent[n * LB + 256 + tid];
    __syncthreads();

    unsigned long long ci =
        ((unsigned long long)__float_as_uint(sh[i]) << 32) | (unsigned int)i;
    int r = 0;
    int j0 = slice * 32;
#pragma unroll 8
    for (int j = j0; j < j0 + 32; ++j) {      // LDS broadcast reads
        unsigned long long cj =
            ((unsigned long long)__float_as_uint(sh[j]) << 32) | (unsigned int)j;
        r += (cj < ci) ? 1 : 0;
    }
    r += __shfl_xor(r, 1, 64);
    r += __shfl_xor(r, 2, 64);
    r += __shfl_xor(r, 4, 64);
    r += __shfl_xor(r, 8, 64);                // full rank in all 16 lanes
    if (slice == 0) {
        out_rest[n * LB + i] = (float)r;
        out_mask[n * LB + i] = (r < LEN_KEEP) ? 0.0f : 1.0f;
        if (r < LEN_KEEP) {
            int e = atomicAdd(&nkeep, 1);
            keep_list[e] = (r << 16) | i;
        }
    }
    __syncthreads();

    int nk = nkeep;
    for (int e = 0; e < nk; ++e) {
        int ent_ri = keep_list[e];
        int slot = ent_ri >> 16;
        int rowi = ent_ri & 0xFFFF;
        const float4* src = (const float4*)(x + ((size_t)(n * LB + rowi)) * DB);
        float4* dst = (float4*)(out_x + ((size_t)(n * LEN_KEEP + slot)) * DB);
        dst[tid] = src[tid];     // 256 threads x 16B = one full 4KB row
    }
}

extern "C" void kernel_launch(void* const* d_in, const int* in_sizes, int n_in,
                              void* d_out, int out_size, void* d_ws, size_t ws_size,
                              hipStream_t stream) {
    const float* x   = (const float*)d_in[0];   // (4,512,1024)
    const float* img = (const float*)d_in[1];   // (4,512,768)

    float* out      = (float*)d_out;
    float* out_x    = out;                               // 4*128*1024
    float* out_mask = out + (size_t)NB * LEN_KEEP * DB;  // 4*512
    float* out_rest = out_mask + NB * LB;                // 4*512

    float* ws   = (float*)d_ws;
    float* bmin = ws;            // 64
    float* bmax = ws + 64;       // 64
    float* ent  = ws + 128;      // 2048

    minmax_partial<<<64, 256, 0, stream>>>((const float4*)img, bmin, bmax);
    entropy_kernel<<<NB * LB, 256, 0, stream>>>(img, bmin, bmax, ent);
    rank_gather_kernel<<<128, 256, 0, stream>>>(x, ent, out_x, out_mask, out_rest);
}